// Round 3
// baseline (455.411 us; speedup 1.0000x reference)
//
#include <hip/hip_runtime.h>
#include <hip/hip_bf16.h>

#define N_   32
#define C_   2048
#define ST_  16
#define H_   64      // ST*ALPHA
#define K_   3
#define CB_  512
#define LT_  400
#define LTP_ 402     // per-n padded t rows (1 zero row each side)
#define LTROWS_ (N_ * LTP_ + 144)   // + staging overrun tail (garbage OK, masked)

using bf16x8 = __attribute__((ext_vector_type(8))) __bf16;
using f32x4  = __attribute__((ext_vector_type(4))) float;
typedef unsigned short ushort_t;

__device__ __forceinline__ unsigned short f2bf(float f) {
    unsigned int u = __float_as_uint(f);
    u = (u + 0x7fffu + ((u >> 16) & 1u)) >> 16;
    return (unsigned short)u;
}
__device__ __forceinline__ float bf2f(unsigned short h) {
    return __uint_as_float(((unsigned int)h) << 16);
}

// async global->LDS, 16 B/lane: lane i lands at ldsbase + i*16 (wave-uniform base)
__device__ __forceinline__ void gload16(const ushort_t* g, ushort_t* l) {
    __builtin_amdgcn_global_load_lds(
        (const __attribute__((address_space(1))) unsigned int*)g,
        (__attribute__((address_space(3))) unsigned int*)l, 16, 0, 0);
}

// ---------------- P0: global branch -> per-(n,c) softmax kernel [NC,4] fp32
__global__ __launch_bounds__(256) void k_global(
    const float* __restrict__ st, const float* __restrict__ g_w1,
    const float* __restrict__ gam, const float* __restrict__ bet,
    const float* __restrict__ mean, const float* __restrict__ var,
    const float* __restrict__ g_w2, float* __restrict__ kern) {
    __shared__ float w1[H_][ST_];
    __shared__ float sc[H_], bi[H_];
    __shared__ float w2[K_][H_];
    int tid = threadIdx.x;
    for (int i = tid; i < H_ * ST_; i += 256) w1[i / ST_][i % ST_] = g_w1[i];
    if (tid < H_) {
        float s = gam[tid] * rsqrtf(var[tid] + 1e-5f);
        sc[tid] = s;
        bi[tid] = bet[tid] - mean[tid] * s;
    }
    for (int i = tid; i < K_ * H_; i += 256) w2[i / H_][i % H_] = g_w2[i];
    __syncthreads();
    int row = blockIdx.x * 256 + tid;  // n*C + c
    const float* p = st + (size_t)row * ST_;
    float s[ST_];
#pragma unroll
    for (int i = 0; i < ST_; ++i) s[i] = p[i];
    float lg0 = 0.f, lg1 = 0.f, lg2 = 0.f;
    for (int j = 0; j < H_; ++j) {
        float h = 0.f;
#pragma unroll
        for (int i = 0; i < ST_; ++i) h = fmaf(w1[j][i], s[i], h);
        h = fmaxf(fmaf(h, sc[j], bi[j]), 0.f);
        lg0 = fmaf(w2[0][j], h, lg0);
        lg1 = fmaf(w2[1][j], h, lg1);
        lg2 = fmaf(w2[2][j], h, lg2);
    }
    float m = fmaxf(lg0, fmaxf(lg1, lg2));
    float e0 = __expf(lg0 - m), e1 = __expf(lg1 - m), e2 = __expf(lg2 - m);
    float inv = 1.f / (e0 + e1 + e2);
    float4 o = make_float4(e0 * inv, e1 * inv, e2 * inv, 0.f);
    *(float4*)(kern + (size_t)row * 4) = o;
}

// ---------------- P1: transpose lt [n][c][t] fp32 -> ltT [n][t+1][c] bf16
__global__ __launch_bounds__(256) void k_transpose(
    const float* __restrict__ lt, ushort_t* __restrict__ ltT) {
    __shared__ float tile[32][33];
    int tt = blockIdx.x * 32;
    int cc = blockIdx.y * 32;
    int n  = blockIdx.z;
    const float* src = lt + ((size_t)n * C_ + cc) * LT_;
    int tx = threadIdx.x & 31, ty = threadIdx.x >> 5;  // ty 0..7
#pragma unroll
    for (int i = 0; i < 4; ++i) {
        int c = ty + i * 8;
        int t = tt + tx;
        tile[c][tx] = (t < LT_) ? src[(size_t)c * LT_ + t] : 0.f;
    }
    __syncthreads();
    ushort_t* dst = ltT + (size_t)n * LTP_ * C_;
#pragma unroll
    for (int i = 0; i < 4; ++i) {
        int tl = ty + i * 8;
        int t = tt + tl;
        if (t < LT_) dst[(size_t)(t + 1) * C_ + cc + tx] = f2bf(tile[tx][tl]);
    }
}

// zero the two pad rows of ltT per n
__global__ __launch_bounds__(256) void k_zero(ushort_t* __restrict__ ltT) {
    int i = blockIdx.x * 256 + threadIdx.x;  // over N*C
    int n = i >> 11, c = i & (C_ - 1);
    size_t base = (size_t)n * LTP_ * C_;
    ltT[base + c] = 0;
    ltT[base + (size_t)(LTP_ - 1) * C_ + c] = 0;
}

// ---------------- P2: repack l_w1 [cb][c][k] -> w1b[k][cb][c] bf16
__global__ __launch_bounds__(256) void k_w1(
    const float* __restrict__ l_w1, ushort_t* __restrict__ w1b) {
    int i = blockIdx.x * 256 + threadIdx.x;  // over CB*C
    float a = l_w1[(size_t)i * 3 + 0];
    float b = l_w1[(size_t)i * 3 + 1];
    float c = l_w1[(size_t)i * 3 + 2];
    w1b[0 * (size_t)CB_ * C_ + i] = f2bf(a);
    w1b[1 * (size_t)CB_ * C_ + i] = f2bf(b);
    w1b[2 * (size_t)CB_ * C_ + i] = f2bf(c);
}

// ---------------- P3: convert l_w2 [c][cb] -> bf16
__global__ __launch_bounds__(256) void k_w2(
    const float* __restrict__ l_w2, ushort_t* __restrict__ w2b) {
    int i = blockIdx.x * 256 + threadIdx.x;  // over C*CB
    w2b[i] = f2bf(l_w2[i]);
}

// ---------------- G1: X[n*400+t][cb] = ReLU(BN(sum_k W1k @ lt_shift_k)), bf16
// 128(M=t) x 64(N=cb) tile, grid (4,8,32)=1024 blocks = 4/CU exactly.
// Unpadded 64B LDS rows; async global_load_lds staging; waves 2x2 (64Mx32N).
#define BK 32

__global__ __launch_bounds__(256, 4) void k_gemm1(
    const ushort_t* __restrict__ ltT, const ushort_t* __restrict__ w1b,
    const float* __restrict__ bn_g, const float* __restrict__ bn_b,
    const float* __restrict__ bn_m, const float* __restrict__ bn_v,
    ushort_t* __restrict__ Xws) {
    __shared__ __align__(16) ushort_t Asm[144 * 32];  // 9 chunks of 16 rows x 64B
    __shared__ __align__(16) ushort_t Bsm[192 * 32];  // 12 chunks (3 taps x 64 rows)
    const int tid = threadIdx.x;
    const int n   = blockIdx.z;
    const int tm  = blockIdx.x * 128;
    const int cb0 = blockIdx.y * 64;
    const int lane = tid & 63, lrow = lane & 15, quad = lane >> 4;
    const int wv = tid >> 6, wvM = wv & 1, wvN = wv >> 1;

    f32x4 acc[4][2];
#pragma unroll
    for (int i = 0; i < 4; ++i)
#pragma unroll
        for (int j = 0; j < 2; ++j) acc[i][j] = (f32x4){0.f, 0.f, 0.f, 0.f};

    // per-lane global bases: row = lane>>2, k-quad = lane&3 (16B)
    const ushort_t* aBase = ltT + ((size_t)n * LTP_ + tm + (lane >> 2)) * C_ + (lane & 3) * 8;
    const ushort_t* bBase = w1b + ((size_t)cb0 + (lane >> 2)) * C_ + (lane & 3) * 8;

    for (int c0 = 0; c0 < C_; c0 += BK) {
        __syncthreads();
        // 21 chunks: 9 A + 12 B, distributed across the 4 waves
        for (int cc = wv; cc < 21; cc += 4) {
            if (cc < 9) {
                gload16(aBase + (size_t)cc * 16 * C_ + c0, Asm + cc * 512);
            } else {
                int j = cc - 9;  // tap = j>>2, row-chunk = j&3
                gload16(bBase + ((size_t)(j >> 2) * CB_ + (j & 3) * 16) * C_ + c0,
                        Bsm + j * 512);
            }
        }
        __syncthreads();

        bf16x8 bfr[3][2];
#pragma unroll
        for (int k = 0; k < 3; ++k)
#pragma unroll
            for (int nf = 0; nf < 2; ++nf)
                bfr[k][nf] = *(const bf16x8*)&Bsm[(k * 64 + wvN * 32 + nf * 16 + lrow) * 32 + quad * 8];
#pragma unroll
        for (int mf = 0; mf < 4; ++mf) {
            bf16x8 af[3];
#pragma unroll
            for (int k = 0; k < 3; ++k)
                af[k] = *(const bf16x8*)&Asm[(wvM * 64 + mf * 16 + lrow + k) * 32 + quad * 8];
#pragma unroll
            for (int nf = 0; nf < 2; ++nf)
#pragma unroll
                for (int k = 0; k < 3; ++k)
                    acc[mf][nf] = __builtin_amdgcn_mfma_f32_16x16x32_bf16(af[k], bfr[k][nf], acc[mf][nf], 0, 0, 0);
        }
    }
    // epilogue: BN+ReLU per cb, store bf16 to Xws[n*400+t][cb], mask t<400
    float s[2], bo[2];
#pragma unroll
    for (int nf = 0; nf < 2; ++nf) {
        int cb = cb0 + wvN * 32 + nf * 16 + lrow;
        float sc = bn_g[cb] * rsqrtf(bn_v[cb] + 1e-5f);
        s[nf] = sc;
        bo[nf] = bn_b[cb] - bn_m[cb] * sc;
    }
    const int tBase = tm + wvM * 64 + quad * 4;
#pragma unroll
    for (int mf = 0; mf < 4; ++mf) {
#pragma unroll
        for (int r = 0; r < 4; ++r) {
            int t = tBase + mf * 16 + r;
            if (t < LT_) {
#pragma unroll
                for (int nf = 0; nf < 2; ++nf) {
                    int cb = cb0 + wvN * 32 + nf * 16 + lrow;
                    float v = fmaxf(fmaf(acc[mf][nf][r], s[nf], bo[nf]), 0.f);
                    Xws[((size_t)n * LT_ + t) * CB_ + cb] = f2bf(v);
                }
            }
        }
    }
}

// ---------------- G2: newlt[n][c][t] = lt * sigmoid(W2 @ X)
// M=c (tile 128), N=flat (n,t) (12800 rows, tile 128, 100 tiles exact), K=cb.
__global__ __launch_bounds__(256, 4) void k_gemm2(
    const ushort_t* __restrict__ Xws, const ushort_t* __restrict__ w2b,
    const float* __restrict__ lt, ushort_t* __restrict__ newlt) {
    __shared__ __align__(16) ushort_t Asm[128 * 32];
    __shared__ __align__(16) ushort_t Bsm[128 * 32];
    const int tid = threadIdx.x;
    const int cm = blockIdx.x * 128;
    const int tt = blockIdx.y * 128;  // flat (n,t) base
    const int lane = tid & 63, lrow = lane & 15, quad = lane >> 4;
    const int wv = tid >> 6, wvM = wv & 1, wvN = wv >> 1;

    f32x4 acc[4][4];
#pragma unroll
    for (int i = 0; i < 4; ++i)
#pragma unroll
        for (int j = 0; j < 4; ++j) acc[i][j] = (f32x4){0.f, 0.f, 0.f, 0.f};

    const ushort_t* aBase = w2b + ((size_t)cm + (lane >> 2)) * CB_ + (lane & 3) * 8;
    const ushort_t* bBase = Xws + ((size_t)tt + (lane >> 2)) * CB_ + (lane & 3) * 8;

    for (int k0 = 0; k0 < CB_; k0 += BK) {
        __syncthreads();
        for (int cc = wv; cc < 16; cc += 4) {
            if (cc < 8)
                gload16(aBase + (size_t)cc * 16 * CB_ + k0, Asm + cc * 512);
            else {
                int j = cc - 8;
                gload16(bBase + (size_t)j * 16 * CB_ + k0, Bsm + j * 512);
            }
        }
        __syncthreads();

        bf16x8 af[4], bfm[4];
#pragma unroll
        for (int mf = 0; mf < 4; ++mf)
            af[mf] = *(const bf16x8*)&Asm[(wvM * 64 + mf * 16 + lrow) * 32 + quad * 8];
#pragma unroll
        for (int nf = 0; nf < 4; ++nf)
            bfm[nf] = *(const bf16x8*)&Bsm[(wvN * 64 + nf * 16 + lrow) * 32 + quad * 8];
#pragma unroll
        for (int mf = 0; mf < 4; ++mf)
#pragma unroll
            for (int nf = 0; nf < 4; ++nf)
                acc[mf][nf] = __builtin_amdgcn_mfma_f32_16x16x32_bf16(af[mf], bfm[nf], acc[mf][nf], 0, 0, 0);
    }
    // epilogue: sigmoid, multiply by lt, store bf16 newlt[n][c][t]
#pragma unroll
    for (int mf = 0; mf < 4; ++mf) {
#pragma unroll
        for (int r = 0; r < 4; ++r) {
            int c = cm + wvM * 64 + mf * 16 + quad * 4 + r;
#pragma unroll
            for (int nf = 0; nf < 4; ++nf) {
                unsigned int flatm = tt + wvN * 64 + nf * 16 + lrow;
                unsigned int n2 = flatm / 400u;
                unsigned int t2 = flatm - n2 * 400u;
                size_t off = ((size_t)n2 * C_ + c) * LT_ + t2;
                float g = 1.f / (1.f + __expf(-acc[mf][nf][r]));
                newlt[off] = f2bf(lt[off] * g);
            }
        }
    }
}

// ---------------- G3: out[n][c][t] = sum_i kern[n][c][i] * newlt[t+i-1]
__global__ __launch_bounds__(256) void k_final(
    const ushort_t* __restrict__ newlt, const float* __restrict__ kern,
    float* __restrict__ out) {
    long long idx = (long long)blockIdx.x * 256 + threadIdx.x;  // over N*C*100
    int t0 = (int)(idx % 100) * 4;
    long long nc = idx / 100;
    const ushort_t* np = newlt + (size_t)nc * LT_;
    float4 kv = *(const float4*)(kern + (size_t)nc * 4);
    float nl[6];
#pragma unroll
    for (int j = -1; j <= 4; ++j) {
        int t = t0 + j;
        nl[j + 1] = (t >= 0 && t < LT_) ? bf2f(np[t]) : 0.f;
    }
    float4 o;
    o.x = kv.x * nl[0] + kv.y * nl[1] + kv.z * nl[2];
    o.y = kv.x * nl[1] + kv.y * nl[2] + kv.z * nl[3];
    o.z = kv.x * nl[2] + kv.y * nl[3] + kv.z * nl[4];
    o.w = kv.x * nl[3] + kv.y * nl[4] + kv.z * nl[5];
    *(float4*)(out + (size_t)nc * LT_ + t0) = o;
}

extern "C" void kernel_launch(void* const* d_in, const int* in_sizes, int n_in,
                              void* d_out, int out_size, void* d_ws, size_t ws_size,
                              hipStream_t stream) {
    const float* st   = (const float*)d_in[0];
    const float* lt   = (const float*)d_in[1];
    const float* g_w1 = (const float*)d_in[2];
    const float* g_bg = (const float*)d_in[3];
    const float* g_bb = (const float*)d_in[4];
    const float* g_bm = (const float*)d_in[5];
    const float* g_bv = (const float*)d_in[6];
    const float* g_w2 = (const float*)d_in[7];
    const float* l_w1 = (const float*)d_in[8];
    const float* l_bg = (const float*)d_in[9];
    const float* l_bb = (const float*)d_in[10];
    const float* l_bm = (const float*)d_in[11];
    const float* l_bv = (const float*)d_in[12];
    const float* l_w2 = (const float*)d_in[13];
    float* out = (float*)d_out;

    char* ws = (char*)d_ws;
    // workspace layout (bytes)
    float*    kern = (float*)(ws + 0);                    // 1,048,576
    ushort_t* w1b  = (ushort_t*)(ws + 1048576);           // 6,291,456
    ushort_t* w2b  = (ushort_t*)(ws + 7340032);           // 2,097,152
    ushort_t* Xws  = (ushort_t*)(ws + 9437184);           // 13,107,200
    ushort_t* ltT  = (ushort_t*)(ws + 22544384);          // 13008*2048*2 = 53,280,768
    ushort_t* newlt = ltT;                                // alias: ltT dead after G1

    k_global<<<dim3((N_ * C_) / 256), dim3(256), 0, stream>>>(
        st, g_w1, g_bg, g_bb, g_bm, g_bv, g_w2, kern);
    k_w1<<<dim3((CB_ * C_) / 256), dim3(256), 0, stream>>>(l_w1, w1b);
    k_w2<<<dim3((C_ * CB_) / 256), dim3(256), 0, stream>>>(l_w2, w2b);
    k_zero<<<dim3((N_ * C_) / 256), dim3(256), 0, stream>>>(ltT);
    k_transpose<<<dim3(13, C_ / 32, N_), dim3(256), 0, stream>>>(lt, ltT);
    k_gemm1<<<dim3(4, 8, N_), dim3(256), 0, stream>>>(
        ltT, w1b, l_bg, l_bb, l_bm, l_bv, Xws);
    k_gemm2<<<dim3(C_ / 128, 100, 1), dim3(256), 0, stream>>>(Xws, w2b, lt, newlt);
    k_final<<<dim3((N_ * C_ * (LT_ / 4)) / 256), dim3(256), 0, stream>>>(
        newlt, kern, out);
}